// Round 10
// baseline (123.218 us; speedup 1.0000x reference)
//
#include <hip/hip_runtime.h>

// PAFA loss, MI355X. N=262144 rows, D=256 cols, P=512 patients.
//   within  = sum||x||^2 - sum_p cnt_p*||c_p||^2
//   between = P*sum||c_p||^2 - ||sum_p c_p||^2   (T = sum_p c_p, TT = ||T||^2)
//   gpal    = S2/P - TT/P^2
//   loss    = 0.1*within/(between+1e-6) + 0.1*gpal
//
// Pipeline (4 dispatches):
//   k_hist    per-block hists -> bh[pat][blk]; zeros gsums/T/scalars/done
//   k_scatter per-block scan recompute -> dense sorted idx (no padding)
//   k_mainf   FLAT 512-row chunks (perfect balance), R7 hot loop, per-segment
//             LDS partials -> global atomic flush to gsums
//   k_cent    centroids from gsums -> T/S1/S2; done-counter fused final
//
// R5: never scalarize gather addresses (readlane) -> serial chain.
// R6: don't put heavy (double/fence) tails in the gather kernel -> regalloc.
// R7: TLP (32 waves/CU) is the robust latency hider; keep hot kernel lean.
// R8: dispatch boundaries >> device-scope spin barriers.
// R9: per-patient blocks leave a ~14% max-count tail; flat chunks fix it.

#define DIMS 256
#define NPAT 512
#define HB 64        // hist/scatter blocks
#define HT 1024      // threads per hist/scatter block
#define MT 1024      // mainf threads per block
#define MW 16        // mainf waves per block
#define CH 512       // rows per mainf block (N = 512*512 exactly)
#define MAXSEG 6     // max patient segments per 512-row chunk (true max ~3)

// ws layout (bytes):
//   0      counts  u32[512]
//   2048   starts  u32[512]  (exact exclusive prefix, unpadded)
//   4096   scalars f32[4] = {SumSq, S1, S2, -}
//   4352   done    u32
//   4608   T       f32[256]
//   8192   bh      u32[512*64] [pat][blk] raw counts (128 KB)
//   139264 gsums   f32[512*256] (512 KB)
//   663552 idx     u32[N] (1 MB)

extern "C" __global__ void __launch_bounds__(HT)
k_hist(const int* __restrict__ pids, int N, unsigned* __restrict__ bh,
       float* __restrict__ gsums, float* __restrict__ scalars,
       float* __restrict__ T, unsigned* __restrict__ done)
{
    __shared__ unsigned h[NPAT];
    const int t = threadIdx.x;
    if (t < NPAT) h[t] = 0u;
    __syncthreads();

    const int r = (blockIdx.x * HT + t) * 4;   // N = HB*HT*4 = 262144 exactly
    if (r + 3 < N) {
        const int4 p4 = *reinterpret_cast<const int4*>(pids + r);
        atomicAdd(&h[p4.x], 1u);
        atomicAdd(&h[p4.y], 1u);
        atomicAdd(&h[p4.z], 1u);
        atomicAdd(&h[p4.w], 1u);
    } else {
        for (int k = 0; k < 4; ++k)
            if (r + k < N) atomicAdd(&h[pids[r + k]], 1u);
    }
    __syncthreads();
    if (t < NPAT) bh[t * HB + blockIdx.x] = h[t];

    // zero next-dispatch accumulators (64*1024 float2 = 512 KB exactly)
    reinterpret_cast<float2*>(gsums)[blockIdx.x * HT + t] = make_float2(0.f, 0.f);
    if (blockIdx.x == 0) {
        if (t < 4)    scalars[t] = 0.0f;
        if (t == 4)   *done      = 0u;
        if (t < DIMS) T[t]       = 0.0f;
    }
}

// Scatter with per-block scan recompute (R9-proven), unpadded starts.
extern "C" __global__ void __launch_bounds__(HT)
k_scatter(const int* __restrict__ pids, int N,
          const unsigned* __restrict__ bh, unsigned* __restrict__ counts,
          unsigned* __restrict__ starts, unsigned* __restrict__ idx)
{
    __shared__ unsigned tmp[NPAT];
    __shared__ unsigned basec[NPAT];

    const int t   = threadIdx.x;
    const int blk = blockIdx.x;

    unsigned total = 0u, pref = 0u;
    if (t < NPAT) {
        const uint4* row = reinterpret_cast<const uint4*>(bh + t * HB);
        #pragma unroll
        for (int k = 0; k < HB / 4; ++k) {
            const uint4 v = row[k];
            const int b0 = 4 * k;
            pref  += (b0 + 0 < blk ? v.x : 0u);
            pref  += (b0 + 1 < blk ? v.y : 0u);
            pref  += (b0 + 2 < blk ? v.z : 0u);
            pref  += (b0 + 3 < blk ? v.w : 0u);
            total += v.x + v.y + v.z + v.w;
        }
        tmp[t] = total;
    }
    __syncthreads();
    for (int off = 1; off < NPAT; off <<= 1) {
        const unsigned v = (t >= off && t < NPAT) ? tmp[t - off] : 0u;
        __syncthreads();
        if (t < NPAT) tmp[t] += v;
        __syncthreads();
    }
    if (t < NPAT) {
        const unsigned st = tmp[t] - total;    // exact exclusive prefix
        basec[t] = st + pref;
        if (blk == 0) { starts[t] = st; counts[t] = total; }
    }
    __syncthreads();

    const int r = (blk * HT + t) * 4;
    if (r + 3 < N) {
        const int4 p4 = *reinterpret_cast<const int4*>(pids + r);
        idx[atomicAdd(&basec[p4.x], 1u)] = (unsigned)(r + 0);
        idx[atomicAdd(&basec[p4.y], 1u)] = (unsigned)(r + 1);
        idx[atomicAdd(&basec[p4.z], 1u)] = (unsigned)(r + 2);
        idx[atomicAdd(&basec[p4.w], 1u)] = (unsigned)(r + 3);
    } else {
        for (int k = 0; k < 4; ++k)
            if (r + k < N)
                idx[atomicAdd(&basec[pids[r + k]], 1u)] = (unsigned)(r + k);
    }
}

// Flat chunks: block b owns sorted positions [b*512, b*512+512). 16 waves,
// wave w takes batches q = c0+4w, +64, ... (8 per wave). Fast path = R7 body;
// segment boundaries are wave-uniform position compares against starts.
extern "C" __global__ void __launch_bounds__(MT, 4)
k_mainf(const float* __restrict__ feats, const unsigned* __restrict__ idx,
        const unsigned* __restrict__ starts, int N,
        float* __restrict__ gsums, float* __restrict__ scalars)
{
    __shared__ float    part[MAXSEG][DIMS];   // 6 KB
    __shared__ float    sred[MW];
    __shared__ unsigned sh_start[NPAT];       // 2 KB
    __shared__ unsigned sh_nseg;
    __shared__ unsigned sh_bound[MAXSEG];     // end position of segment s
    __shared__ unsigned sh_pat[MAXSEG];       // patient of segment s

    const int t    = threadIdx.x;
    const int lane = t & 63;
    const int w    = t >> 6;                  // wave 0..15
    const unsigned c0 = (unsigned)blockIdx.x * CH;
    const unsigned c1 = c0 + CH;

    if (t < NPAT) sh_start[t] = starts[t];
    for (int i = t; i < MAXSEG * DIMS; i += MT)
        reinterpret_cast<float*>(part)[i] = 0.f;
    __syncthreads();

    if (t == 0) {
        // largest p with sh_start[p] <= c0
        unsigned lo = 0, hi = NPAT - 1;
        while (lo < hi) {
            const unsigned mid = (lo + hi + 1) >> 1;
            if (sh_start[mid] <= c0) lo = mid; else hi = mid - 1;
        }
        unsigned ns = 0, p = lo;
        while (true) {
            const unsigned end = (p + 1 < NPAT) ? sh_start[p + 1] : (unsigned)N;
            sh_pat[ns]   = p;
            sh_bound[ns] = (end < c1) ? end : c1;
            ns++;
            if (end >= c1 || ns >= MAXSEG) break;
            p++;
        }
        sh_nseg = ns;
    }
    __syncthreads();

    const unsigned nseg = sh_nseg;
    unsigned seg = 0;
    {
        const unsigned sp = c0 + 4u * (unsigned)w;
        while (seg + 1 < nseg && sp >= sh_bound[seg]) seg++;
    }
    unsigned bnd = sh_bound[seg];

    float ax = 0.f, ay = 0.f, az = 0.f, aw = 0.f;
    float ssq = 0.f;
    const unsigned base = lane * 4;

    for (unsigned q = c0 + 4u * (unsigned)w; q < c1; q += 4u * MW) {
        const uint4 cid = *reinterpret_cast<const uint4*>(idx + q);
        if (q + 4u <= bnd) {
            // fast path (R7-proven body)
            const float4 v0 = *reinterpret_cast<const float4*>(feats + (size_t)cid.x * DIMS + base);
            const float4 v1 = *reinterpret_cast<const float4*>(feats + (size_t)cid.y * DIMS + base);
            const float4 v2 = *reinterpret_cast<const float4*>(feats + (size_t)cid.z * DIMS + base);
            const float4 v3 = *reinterpret_cast<const float4*>(feats + (size_t)cid.w * DIMS + base);
            ax += v0.x + v1.x + v2.x + v3.x;
            ay += v0.y + v1.y + v2.y + v3.y;
            az += v0.z + v1.z + v2.z + v3.z;
            aw += v0.w + v1.w + v2.w + v3.w;
            ssq += v0.x*v0.x + v0.y*v0.y + v0.z*v0.z + v0.w*v0.w;
            ssq += v1.x*v1.x + v1.y*v1.y + v1.z*v1.z + v1.w*v1.w;
            ssq += v2.x*v2.x + v2.y*v2.y + v2.z*v2.z + v2.w*v2.w;
            ssq += v3.x*v3.x + v3.y*v3.y + v3.z*v3.z + v3.w*v3.w;
        } else {
            // straddle / segment-advance path (rare; wave-uniform control)
            const unsigned rows[4] = { cid.x, cid.y, cid.z, cid.w };
            #pragma unroll
            for (int k = 0; k < 4; ++k) {
                while (q + (unsigned)k >= bnd) {   // flush & advance (uniform)
                    atomicAdd(&part[seg][base + 0], ax);
                    atomicAdd(&part[seg][base + 1], ay);
                    atomicAdd(&part[seg][base + 2], az);
                    atomicAdd(&part[seg][base + 3], aw);
                    ax = ay = az = aw = 0.f;
                    seg++;
                    bnd = sh_bound[seg];
                }
                const float4 v = *reinterpret_cast<const float4*>(
                    feats + (size_t)rows[k] * DIMS + base);
                ax += v.x; ay += v.y; az += v.z; aw += v.w;
                ssq += v.x*v.x + v.y*v.y + v.z*v.z + v.w*v.w;
            }
        }
    }
    // final flush
    atomicAdd(&part[seg][base + 0], ax);
    atomicAdd(&part[seg][base + 1], ay);
    atomicAdd(&part[seg][base + 2], az);
    atomicAdd(&part[seg][base + 3], aw);

    for (int off = 32; off; off >>= 1) ssq += __shfl_down(ssq, off, 64);
    if (lane == 0) sred[w] = ssq;
    __syncthreads();

    // flush per-segment partials to global sums
    for (unsigned i = (unsigned)t; i < nseg * DIMS; i += MT) {
        const unsigned s = i >> 8, d = i & 255u;
        atomicAdd(&gsums[sh_pat[s] * DIMS + d], part[s][d]);
    }
    if (t == 0) {
        float sq = 0.f;
        #pragma unroll
        for (int ww = 0; ww < MW; ++ww) sq += sred[ww];
        atomicAdd(&scalars[0], sq);           // SumSq
    }
}

// Centroids from complete gsums; done-counter fused final (R4-proven pattern).
extern "C" __global__ void __launch_bounds__(DIMS)
k_cent(const float* __restrict__ gsums, const unsigned* __restrict__ counts,
       float* __restrict__ T, float* __restrict__ scalars,
       unsigned* __restrict__ done, const int* __restrict__ nump,
       float* __restrict__ out)
{
    __shared__ float cred[4];
    __shared__ float red[4];
    __shared__ unsigned lastflag;

    const int p = blockIdx.x;
    const int d = threadIdx.x;

    const float s    = gsums[p * DIMS + d];
    const float cntf = fmaxf((float)counts[p], 1.0f);
    const float c    = s / cntf;
    atomicAdd(&T[d], c);

    float csq = c * c;
    for (int off = 32; off; off >>= 1) csq += __shfl_down(csq, off, 64);
    if ((d & 63) == 0) cred[d >> 6] = csq;
    __syncthreads();
    if (d == 0) {
        const float s2p = cred[0] + cred[1] + cred[2] + cred[3];
        atomicAdd(&scalars[2], s2p);          // S2 += ||c_p||^2
        atomicAdd(&scalars[1], cntf * s2p);   // S1 += cnt_p * ||c_p||^2
    }

    __threadfence();
    if (d == 0) {
        const unsigned prev = __hip_atomic_fetch_add(
            done, 1u, __ATOMIC_ACQ_REL, __HIP_MEMORY_SCOPE_AGENT);
        lastflag = (prev == (unsigned)(gridDim.x - 1)) ? 1u : 0u;
    }
    __syncthreads();
    if (lastflag) {
        const float tv = __hip_atomic_load(&T[d], __ATOMIC_RELAXED,
                                           __HIP_MEMORY_SCOPE_AGENT);
        float tt = tv * tv;
        for (int off = 32; off; off >>= 1) tt += __shfl_down(tt, off, 64);
        if ((d & 63) == 0) red[d >> 6] = tt;
        __syncthreads();
        if (d == 0) {
            const double TT    = (double)red[0] + red[1] + red[2] + red[3];
            const double SumSq = (double)__hip_atomic_load(&scalars[0],
                __ATOMIC_RELAXED, __HIP_MEMORY_SCOPE_AGENT);
            const double S1 = (double)__hip_atomic_load(&scalars[1],
                __ATOMIC_RELAXED, __HIP_MEMORY_SCOPE_AGENT);
            const double S2 = (double)__hip_atomic_load(&scalars[2],
                __ATOMIC_RELAXED, __HIP_MEMORY_SCOPE_AGENT);
            const double Pd = (double)(*nump);
            const double within  = SumSq - S1;
            const double between = Pd * S2 - TT;
            const double pcsl = within / (between + 1e-6);
            const double gpal = S2 / Pd - TT / (Pd * Pd);
            out[0] = (float)(0.1 * pcsl + 0.1 * gpal);
        }
    }
}

extern "C" void kernel_launch(void* const* d_in, const int* in_sizes, int n_in,
                              void* d_out, int out_size, void* d_ws, size_t ws_size,
                              hipStream_t stream)
{
    const float* feats = (const float*)d_in[0];
    const int*   pids  = (const int*)d_in[1];
    const int*   nump  = (const int*)d_in[2];
    float*       out   = (float*)d_out;

    const int N = in_sizes[0] / DIMS;
    const int NB = N / CH;                    // 512 flat blocks

    char* ws = (char*)d_ws;
    unsigned* counts  = (unsigned*)(ws);
    unsigned* starts  = (unsigned*)(ws + 2048);
    float*    scalars = (float*)(ws + 4096);
    unsigned* done    = (unsigned*)(ws + 4352);
    float*    T       = (float*)(ws + 4608);
    unsigned* bh      = (unsigned*)(ws + 8192);
    float*    gsums   = (float*)(ws + 139264);
    unsigned* idx     = (unsigned*)(ws + 663552);

    k_hist   <<<dim3(HB),   dim3(HT),   0, stream>>>(pids, N, bh, gsums,
                                                     scalars, T, done);
    k_scatter<<<dim3(HB),   dim3(HT),   0, stream>>>(pids, N, bh, counts,
                                                     starts, idx);
    k_mainf  <<<dim3(NB),   dim3(MT),   0, stream>>>(feats, idx, starts, N,
                                                     gsums, scalars);
    k_cent   <<<dim3(NPAT), dim3(DIMS), 0, stream>>>(gsums, counts, T, scalars,
                                                     done, nump, out);
}

// Round 11
// 82.855 us; speedup vs baseline: 1.4872x; 1.4872x over previous
//
#include <hip/hip_runtime.h>

// PAFA loss, MI355X. N=262144 rows, D=256 cols, P=512 patients.
//   within  = sum||x||^2 - sum_p cnt_p*||c_p||^2
//   between = P*sum||c_p||^2 - ||sum_p c_p||^2   (T = sum_p c_p, TT = ||T||^2)
//   gpal    = S2/P - TT/P^2
//   loss    = 0.1*within/(between+1e-6) + 0.1*gpal
//
// Pipeline (5 dispatches):
//   k_hist    per-block hists -> bh[pat][blk]; zeros scalars/T
//   k_scatter per-block scan recompute (shfl scan) -> 4-aligned sorted idx
//   k_main    4 sub-blocks per patient (2048 x 8 waves, 2 scheduling rounds
//             for balance), R7 hot loop, NON-ATOMIC partials -> gpart/gssq
//   k_cent    reduce 4 subs -> centroid; fire-and-forget T/S1/S2/SumSq atomics
//   k_final   tiny scalar loss
//
// R5: never scalarize gather addresses (readlane) -> serial chain.
// R6: keep heavy tails out of the gather kernel -> regalloc ruins hot loop.
// R7: TLP is the robust latency hider; keep the hot kernel lean.
// R8: dispatch boundaries >> device-scope spin barriers.
// R10: contended atomics are cheap ONLY fire-and-forget; a threadfence
//      (or same-kernel consumer) exposes ~chain_depth x RMW latency.
//      Drain at dispatch end is pipelined; never fence after hot atomics.

#define DIMS 256
#define NPAT 512
#define HB 64        // hist/scatter blocks
#define HT 1024      // threads per hist/scatter block
#define NSUB 4       // sub-blocks per patient in k_main

// ws layout (bytes):
//   0        counts  u32[512]
//   2048     starts  u32[512]  (4-aligned padded starts)
//   4096     scalars f32[4] = {SumSq, S1, S2, -}
//   4608     T       f32[256]
//   8192     bh      u32[512*64] [pat][blk] raw counts (128 KB)
//   139264   gssq    f32[2048]  (8 KB)
//   147456   gpart   f32[2048*256] (2 MB)
//   2244608  idx     u32[N + 2048]

extern "C" __global__ void __launch_bounds__(HT)
k_hist(const int* __restrict__ pids, int N, unsigned* __restrict__ bh,
       float* __restrict__ scalars, float* __restrict__ T)
{
    __shared__ unsigned h[NPAT];
    const int t = threadIdx.x;
    if (t < NPAT) h[t] = 0u;
    __syncthreads();

    const int r = (blockIdx.x * HT + t) * 4;   // N = HB*HT*4 = 262144 exactly
    if (r + 3 < N) {
        const int4 p4 = *reinterpret_cast<const int4*>(pids + r);
        atomicAdd(&h[p4.x], 1u);
        atomicAdd(&h[p4.y], 1u);
        atomicAdd(&h[p4.z], 1u);
        atomicAdd(&h[p4.w], 1u);
    } else {
        for (int k = 0; k < 4; ++k)
            if (r + k < N) atomicAdd(&h[pids[r + k]], 1u);
    }
    __syncthreads();
    if (t < NPAT) bh[t * HB + blockIdx.x] = h[t];

    if (blockIdx.x == 0) {                 // zero next-dispatch accumulators
        if (t < 4)    scalars[t] = 0.0f;
        if (t < DIMS) T[t]       = 0.0f;
    }
}

// Scatter with per-block scan recompute; shfl-based scan (2 barriers).
extern "C" __global__ void __launch_bounds__(HT)
k_scatter(const int* __restrict__ pids, int N,
          const unsigned* __restrict__ bh, unsigned* __restrict__ counts,
          unsigned* __restrict__ starts, unsigned* __restrict__ idx)
{
    __shared__ unsigned wt[HT / 64];
    __shared__ unsigned basec[NPAT];

    const int t    = threadIdx.x;
    const int lane = t & 63;
    const int wid  = t >> 6;
    const int blk  = blockIdx.x;

    unsigned total = 0u, pref = 0u, padded = 0u;
    if (t < NPAT) {
        const uint4* row = reinterpret_cast<const uint4*>(bh + t * HB);
        #pragma unroll
        for (int k = 0; k < HB / 4; ++k) {
            const uint4 v = row[k];
            const int b0 = 4 * k;
            pref  += (b0 + 0 < blk ? v.x : 0u);
            pref  += (b0 + 1 < blk ? v.y : 0u);
            pref  += (b0 + 2 < blk ? v.z : 0u);
            pref  += (b0 + 3 < blk ? v.w : 0u);
            total += v.x + v.y + v.z + v.w;
        }
        padded = (total + 3u) & ~3u;       // 4-aligned segment
    }

    // inclusive scan of `padded` over 1024 threads (only t<512 meaningful)
    unsigned v = padded;
    #pragma unroll
    for (int off = 1; off < 64; off <<= 1) {
        const unsigned u = __shfl_up(v, off, 64);
        if (lane >= off) v += u;
    }
    if (lane == 63) wt[wid] = v;
    __syncthreads();
    if (t < HT / 64) {
        unsigned x = wt[t];
        #pragma unroll
        for (int off = 1; off < HT / 64; off <<= 1) {
            const unsigned u = __shfl_up(x, off, HT / 64);
            if ((t & (HT / 64 - 1)) >= off) x += u;
        }
        wt[t] = x;
    }
    __syncthreads();
    const unsigned incl = v + (wid > 0 ? wt[wid - 1] : 0u);

    if (t < NPAT) {
        const unsigned st = incl - padded;     // exclusive, 4-aligned
        basec[t] = st + pref;
        if (blk == 0) { starts[t] = st; counts[t] = total; }
    }
    __syncthreads();

    const int r = (blk * HT + t) * 4;
    if (r + 3 < N) {
        const int4 p4 = *reinterpret_cast<const int4*>(pids + r);
        idx[atomicAdd(&basec[p4.x], 1u)] = (unsigned)(r + 0);
        idx[atomicAdd(&basec[p4.y], 1u)] = (unsigned)(r + 1);
        idx[atomicAdd(&basec[p4.z], 1u)] = (unsigned)(r + 2);
        idx[atomicAdd(&basec[p4.w], 1u)] = (unsigned)(r + 3);
    } else {
        for (int k = 0; k < 4; ++k)
            if (r + k < N)
                idx[atomicAdd(&basec[pids[r + k]], 1u)] = (unsigned)(r + k);
    }
}

// 4 sub-blocks per patient, 8 waves each. Sub s owns batches [nb*s/4, nb*(s+1)/4)
// of its patient; wave w strides by 8. Hot loop body identical to R7/R9.
// Partials written NON-atomically to gpart[b][256]; ssq to gssq[b].
extern "C" __global__ void __launch_bounds__(512)
k_main(const float* __restrict__ feats, const unsigned* __restrict__ idx,
       const unsigned* __restrict__ counts, const unsigned* __restrict__ starts,
       float* __restrict__ gpart, float* __restrict__ gssq)
{
    __shared__ float part[8][DIMS];    // 8 KB
    __shared__ float sred[8];

    const int t    = threadIdx.x;
    const int lane = t & 63;
    const int w    = t >> 6;                  // wave 0..7
    const int b    = blockIdx.x;              // 0..NPAT*NSUB-1
    const int p    = b >> 2;
    const int s    = b & 3;
    const unsigned start = starts[p];
    const unsigned cnt   = counts[p];
    const unsigned base  = lane * 4;

    const unsigned nb = cnt >> 2;             // full 4-row batches
    const unsigned bs = (nb * (unsigned)s) >> 2;
    const unsigned be = (nb * (unsigned)(s + 1)) >> 2;

    float ax = 0.f, ay = 0.f, az = 0.f, aw = 0.f;
    float ssq = 0.f;

    for (unsigned q = bs + (unsigned)w; q < be; q += 8) {
        const uint4 cid = *reinterpret_cast<const uint4*>(idx + start + 4u * q);
        const float4 v0 = *reinterpret_cast<const float4*>(feats + (size_t)cid.x * DIMS + base);
        const float4 v1 = *reinterpret_cast<const float4*>(feats + (size_t)cid.y * DIMS + base);
        const float4 v2 = *reinterpret_cast<const float4*>(feats + (size_t)cid.z * DIMS + base);
        const float4 v3 = *reinterpret_cast<const float4*>(feats + (size_t)cid.w * DIMS + base);
        ax += v0.x + v1.x + v2.x + v3.x;
        ay += v0.y + v1.y + v2.y + v3.y;
        az += v0.z + v1.z + v2.z + v3.z;
        aw += v0.w + v1.w + v2.w + v3.w;
        ssq += v0.x*v0.x + v0.y*v0.y + v0.z*v0.z + v0.w*v0.w;
        ssq += v1.x*v1.x + v1.y*v1.y + v1.z*v1.z + v1.w*v1.w;
        ssq += v2.x*v2.x + v2.y*v2.y + v2.z*v2.z + v2.w*v2.w;
        ssq += v3.x*v3.x + v3.y*v3.y + v3.z*v3.z + v3.w*v3.w;
    }
    if (s == 3 && w == 0) {   // remainder rows (cnt & 3)
        for (unsigned rr = nb * 4u; rr < cnt; ++rr) {
            const unsigned row = idx[start + rr];
            const float4 v = *reinterpret_cast<const float4*>(feats + (size_t)row * DIMS + base);
            ax += v.x; ay += v.y; az += v.z; aw += v.w;
            ssq += v.x*v.x + v.y*v.y + v.z*v.z + v.w*v.w;
        }
    }

    part[w][base + 0] = ax;
    part[w][base + 1] = ay;
    part[w][base + 2] = az;
    part[w][base + 3] = aw;
    for (int off = 32; off; off >>= 1) ssq += __shfl_down(ssq, off, 64);
    if (lane == 0) sred[w] = ssq;
    __syncthreads();

    if (t < DIMS) {
        float sum = 0.f;
        #pragma unroll
        for (int ww = 0; ww < 8; ++ww) sum += part[ww][t];
        gpart[(size_t)b * DIMS + t] = sum;    // non-atomic, coalesced
    }
    if (t == 0) {
        float sq = 0.f;
        #pragma unroll
        for (int ww = 0; ww < 8; ++ww) sq += sred[ww];
        gssq[b] = sq;
    }
}

// One block per patient: reduce 4 sub partials -> centroid; fire-and-forget
// atomics (no fence, no same-kernel consumer -> pipelined drain, R10 lesson).
extern "C" __global__ void __launch_bounds__(DIMS)
k_cent(const float* __restrict__ gpart, const float* __restrict__ gssq,
       const unsigned* __restrict__ counts,
       float* __restrict__ T, float* __restrict__ scalars)
{
    __shared__ float cred[4];
    const int p = blockIdx.x;
    const int d = threadIdx.x;

    const float sum = gpart[(size_t)(4 * p + 0) * DIMS + d]
                    + gpart[(size_t)(4 * p + 1) * DIMS + d]
                    + gpart[(size_t)(4 * p + 2) * DIMS + d]
                    + gpart[(size_t)(4 * p + 3) * DIMS + d];
    const float cntf = fmaxf((float)counts[p], 1.0f);
    const float c = sum / cntf;
    atomicAdd(&T[d], c);

    float csq = c * c;
    for (int off = 32; off; off >>= 1) csq += __shfl_down(csq, off, 64);
    if ((d & 63) == 0) cred[d >> 6] = csq;
    __syncthreads();
    if (d == 0) {
        const float s2p = cred[0] + cred[1] + cred[2] + cred[3];
        atomicAdd(&scalars[2], s2p);          // S2 += ||c_p||^2
        atomicAdd(&scalars[1], cntf * s2p);   // S1 += cnt_p * ||c_p||^2
        const float sq = gssq[4 * p + 0] + gssq[4 * p + 1]
                       + gssq[4 * p + 2] + gssq[4 * p + 3];
        atomicAdd(&scalars[0], sq);           // SumSq
    }
}

extern "C" __global__ void __launch_bounds__(DIMS)
k_final(const float* __restrict__ T, const float* __restrict__ scalars,
        const int* __restrict__ nump, float* __restrict__ out)
{
    __shared__ float red[4];
    const int d = threadIdx.x;
    const float t = T[d];
    float tt = t * t;
    for (int off = 32; off; off >>= 1) tt += __shfl_down(tt, off, 64);
    if ((d & 63) == 0) red[d >> 6] = tt;
    __syncthreads();
    if (d == 0) {
        const double TT    = (double)red[0] + red[1] + red[2] + red[3];
        const double SumSq = (double)scalars[0];
        const double S1    = (double)scalars[1];
        const double S2    = (double)scalars[2];
        const double Pd    = (double)(*nump);
        const double within  = SumSq - S1;
        const double between = Pd * S2 - TT;
        const double pcsl = within / (between + 1e-6);
        const double gpal = S2 / Pd - TT / (Pd * Pd);
        out[0] = (float)(0.1 * pcsl + 0.1 * gpal);
    }
}

extern "C" void kernel_launch(void* const* d_in, const int* in_sizes, int n_in,
                              void* d_out, int out_size, void* d_ws, size_t ws_size,
                              hipStream_t stream)
{
    const float* feats = (const float*)d_in[0];
    const int*   pids  = (const int*)d_in[1];
    const int*   nump  = (const int*)d_in[2];
    float*       out   = (float*)d_out;

    const int N = in_sizes[0] / DIMS;

    char* ws = (char*)d_ws;
    unsigned* counts  = (unsigned*)(ws);
    unsigned* starts  = (unsigned*)(ws + 2048);
    float*    scalars = (float*)(ws + 4096);
    float*    T       = (float*)(ws + 4608);
    unsigned* bh      = (unsigned*)(ws + 8192);
    float*    gssq    = (float*)(ws + 139264);
    float*    gpart   = (float*)(ws + 147456);
    unsigned* idx     = (unsigned*)(ws + 2244608);

    k_hist   <<<dim3(HB),          dim3(HT),   0, stream>>>(pids, N, bh,
                                                            scalars, T);
    k_scatter<<<dim3(HB),          dim3(HT),   0, stream>>>(pids, N, bh, counts,
                                                            starts, idx);
    k_main   <<<dim3(NPAT * NSUB), dim3(512),  0, stream>>>(feats, idx, counts,
                                                            starts, gpart, gssq);
    k_cent   <<<dim3(NPAT),        dim3(DIMS), 0, stream>>>(gpart, gssq, counts,
                                                            T, scalars);
    k_final  <<<dim3(1),           dim3(DIMS), 0, stream>>>(T, scalars, nump, out);
}

// Round 12
// 70.008 us; speedup vs baseline: 1.7601x; 1.1835x over previous
//
#include <hip/hip_runtime.h>

// PAFA loss, MI355X. N=262144 rows, D=256 cols, P=512 patients.
//   within  = sum||x||^2 - sum_p cnt_p*||c_p||^2
//   between = P*sum||c_p||^2 - ||sum_p c_p||^2   (T = sum_p c_p, TT = ||T||^2)
//   gpal    = S2/P - TT/P^2
//   loss    = 0.1*within/(between+1e-6) + 0.1*gpal
//
// Pipeline (4 dispatches): hist -> scatter(+per-block scan recompute)
//                          -> main (R7-proven) -> final.
//
// R5: never scalarize gather addresses (readlane) -> serial chain.
// R6: don't fuse heavy tails into k_main -> regalloc ruins hot loop.
// R7: TLP (32 waves/CU) is the robust latency hider; keep k_main lean.
// R8: dispatch boundaries are far cheaper than device-scope spin barriers.
// R10: contended atomics are cheap ONLY fire-and-forget; never fence after.
// R11: sub-block balancing + partial round-trips net negative; this R9
//      4-dispatch structure is the measured optimum (69.3 us).

#define DIMS 256
#define NPAT 512
#define HB 64        // hist/scatter blocks
#define HT 1024      // threads per hist/scatter block
#define MT 1024      // main threads per block
#define MW 16        // main waves per block

// ws layout (bytes):
//   0      counts  u32[512]
//   2048   starts  u32[512]   (4-aligned padded starts)
//   4096   scalars f32[4] = {SumSq, S1, S2, -}
//   4608   T       f32[256]
//   8192   bh      u32[512*64]  [pat][blk] raw counts (128 KB)
//   139264 idx     u32[N + 2048]

extern "C" __global__ void __launch_bounds__(HT)
k_hist(const int* __restrict__ pids, int N, unsigned* __restrict__ bh,
       float* __restrict__ scalars, float* __restrict__ T)
{
    __shared__ unsigned h[NPAT];
    const int t = threadIdx.x;
    if (t < NPAT) h[t] = 0u;
    __syncthreads();

    const int r = (blockIdx.x * HT + t) * 4;   // N = HB*HT*4 = 262144 exactly
    if (r + 3 < N) {
        const int4 p4 = *reinterpret_cast<const int4*>(pids + r);
        atomicAdd(&h[p4.x], 1u);
        atomicAdd(&h[p4.y], 1u);
        atomicAdd(&h[p4.z], 1u);
        atomicAdd(&h[p4.w], 1u);
    } else {
        for (int k = 0; k < 4; ++k)
            if (r + k < N) atomicAdd(&h[pids[r + k]], 1u);
    }
    __syncthreads();
    if (t < NPAT) bh[t * HB + blockIdx.x] = h[t];

    if (blockIdx.x == 0) {                 // zero next-dispatch accumulators
        if (t < 4)    scalars[t] = 0.0f;
        if (t < DIMS) T[t]       = 0.0f;
    }
}

// Scatter with per-block scan recompute: thread t reads bh[t][0..63] (L2),
// computes total (-> counts), prefix below own blk, and the block-wide
// padded exclusive scan (-> starts). Placement via LDS cursors only.
extern "C" __global__ void __launch_bounds__(HT)
k_scatter(const int* __restrict__ pids, int N,
          const unsigned* __restrict__ bh, unsigned* __restrict__ counts,
          unsigned* __restrict__ starts, unsigned* __restrict__ idx)
{
    __shared__ unsigned tmp[NPAT];
    __shared__ unsigned basec[NPAT];

    const int t   = threadIdx.x;
    const int blk = blockIdx.x;

    unsigned total = 0u, pref = 0u, padded = 0u;
    if (t < NPAT) {
        const uint4* row = reinterpret_cast<const uint4*>(bh + t * HB);
        #pragma unroll
        for (int k = 0; k < HB / 4; ++k) {
            const uint4 v = row[k];
            const int b0 = 4 * k;
            pref  += (b0 + 0 < blk ? v.x : 0u);
            pref  += (b0 + 1 < blk ? v.y : 0u);
            pref  += (b0 + 2 < blk ? v.z : 0u);
            pref  += (b0 + 3 < blk ? v.w : 0u);
            total += v.x + v.y + v.z + v.w;
        }
        padded = (total + 3u) & ~3u;       // 4-aligned segment
        tmp[t] = padded;
    }
    __syncthreads();
    for (int off = 1; off < NPAT; off <<= 1) {
        const unsigned v = (t >= off && t < NPAT) ? tmp[t - off] : 0u;
        __syncthreads();
        if (t < NPAT) tmp[t] += v;
        __syncthreads();
    }
    if (t < NPAT) {
        const unsigned st = tmp[t] - padded;   // exclusive, 4-aligned
        basec[t] = st + pref;
        if (blk == 0) { starts[t] = st; counts[t] = total; }
    }
    __syncthreads();

    const int r = (blk * HT + t) * 4;
    if (r + 3 < N) {
        const int4 p4 = *reinterpret_cast<const int4*>(pids + r);
        idx[atomicAdd(&basec[p4.x], 1u)] = (unsigned)(r + 0);
        idx[atomicAdd(&basec[p4.y], 1u)] = (unsigned)(r + 1);
        idx[atomicAdd(&basec[p4.z], 1u)] = (unsigned)(r + 2);
        idx[atomicAdd(&basec[p4.w], 1u)] = (unsigned)(r + 3);
    } else {
        for (int k = 0; k < 4; ++k)
            if (r + k < N)
                idx[atomicAdd(&basec[pids[r + k]], 1u)] = (unsigned)(r + k);
    }
}

// One block per patient, 16 waves. Wave w handles 4-row batches b = w, w+16,...
// Per batch: one aligned uint4 row-id load, then 4 independent per-lane
// float4 gathers. Latency hidden by 32 waves/CU TLP.   [identical to R7]
extern "C" __global__ void __launch_bounds__(MT, 4)
k_main(const float* __restrict__ feats, const unsigned* __restrict__ idx,
       const unsigned* __restrict__ counts, const unsigned* __restrict__ starts,
       float* __restrict__ T, float* __restrict__ scalars)
{
    __shared__ float part[MW][DIMS];   // 16 KB
    __shared__ float sred[MW];
    __shared__ float cred[4];

    const int p    = blockIdx.x;
    const int lane = threadIdx.x & 63;
    const int w    = threadIdx.x >> 6;        // wave 0..15
    const unsigned start = starts[p];
    const unsigned cnt   = counts[p];
    const unsigned base  = lane * 4;

    float ax = 0.f, ay = 0.f, az = 0.f, aw = 0.f;
    float ssq = 0.f;

    const unsigned nb = cnt >> 2;             // full 4-row batches
    for (unsigned b = (unsigned)w; b < nb; b += MW) {
        const uint4 cid = *reinterpret_cast<const uint4*>(idx + start + 4u * b);
        const float4 v0 = *reinterpret_cast<const float4*>(feats + (size_t)cid.x * DIMS + base);
        const float4 v1 = *reinterpret_cast<const float4*>(feats + (size_t)cid.y * DIMS + base);
        const float4 v2 = *reinterpret_cast<const float4*>(feats + (size_t)cid.z * DIMS + base);
        const float4 v3 = *reinterpret_cast<const float4*>(feats + (size_t)cid.w * DIMS + base);
        ax += v0.x + v1.x + v2.x + v3.x;
        ay += v0.y + v1.y + v2.y + v3.y;
        az += v0.z + v1.z + v2.z + v3.z;
        aw += v0.w + v1.w + v2.w + v3.w;
        ssq += v0.x*v0.x + v0.y*v0.y + v0.z*v0.z + v0.w*v0.w;
        ssq += v1.x*v1.x + v1.y*v1.y + v1.z*v1.z + v1.w*v1.w;
        ssq += v2.x*v2.x + v2.y*v2.y + v2.z*v2.z + v2.w*v2.w;
        ssq += v3.x*v3.x + v3.y*v3.y + v3.z*v3.z + v3.w*v3.w;
    }
    if (w == 0) {   // remainder rows (cnt & 3)
        for (unsigned rr = nb * 4u; rr < cnt; ++rr) {
            const unsigned row = idx[start + rr];
            const float4 v = *reinterpret_cast<const float4*>(feats + (size_t)row * DIMS + base);
            ax += v.x; ay += v.y; az += v.z; aw += v.w;
            ssq += v.x*v.x + v.y*v.y + v.z*v.z + v.w*v.w;
        }
    }

    part[w][base + 0] = ax;
    part[w][base + 1] = ay;
    part[w][base + 2] = az;
    part[w][base + 3] = aw;
    for (int off = 32; off; off >>= 1) ssq += __shfl_down(ssq, off, 64);
    if (lane == 0) sred[w] = ssq;
    __syncthreads();

    const int d = threadIdx.x;
    if (d < DIMS) {
        float s = 0.f;
        #pragma unroll
        for (int ww = 0; ww < MW; ++ww) s += part[ww][d];
        const float cntf = fmaxf((float)cnt, 1.0f);
        const float c = s / cntf;
        atomicAdd(&T[d], c);
        float csq = c * c;
        for (int off = 32; off; off >>= 1) csq += __shfl_down(csq, off, 64);
        if ((d & 63) == 0) cred[d >> 6] = csq;
    }
    __syncthreads();

    if (threadIdx.x == 0) {
        const float s2p = cred[0] + cred[1] + cred[2] + cred[3];
        const float cntf = fmaxf((float)cnt, 1.0f);
        atomicAdd(&scalars[2], s2p);          // S2 += ||c_p||^2
        atomicAdd(&scalars[1], cntf * s2p);   // S1 += cnt_p * ||c_p||^2
        float sq = 0.f;
        #pragma unroll
        for (int ww = 0; ww < MW; ++ww) sq += sred[ww];
        atomicAdd(&scalars[0], sq);           // SumSq
    }
}

extern "C" __global__ void __launch_bounds__(DIMS)
k_final(const float* __restrict__ T, const float* __restrict__ scalars,
        const int* __restrict__ nump, float* __restrict__ out)
{
    __shared__ float red[4];
    const int d = threadIdx.x;
    const float t = T[d];
    float tt = t * t;
    for (int off = 32; off; off >>= 1) tt += __shfl_down(tt, off, 64);
    if ((d & 63) == 0) red[d >> 6] = tt;
    __syncthreads();
    if (d == 0) {
        const double TT    = (double)red[0] + red[1] + red[2] + red[3];
        const double SumSq = (double)scalars[0];
        const double S1    = (double)scalars[1];
        const double S2    = (double)scalars[2];
        const double Pd    = (double)(*nump);
        const double within  = SumSq - S1;
        const double between = Pd * S2 - TT;
        const double pcsl = within / (between + 1e-6);
        const double gpal = S2 / Pd - TT / (Pd * Pd);
        out[0] = (float)(0.1 * pcsl + 0.1 * gpal);
    }
}

extern "C" void kernel_launch(void* const* d_in, const int* in_sizes, int n_in,
                              void* d_out, int out_size, void* d_ws, size_t ws_size,
                              hipStream_t stream)
{
    const float* feats = (const float*)d_in[0];
    const int*   pids  = (const int*)d_in[1];
    const int*   nump  = (const int*)d_in[2];
    float*       out   = (float*)d_out;

    const int N = in_sizes[0] / DIMS;

    char* ws = (char*)d_ws;
    unsigned* counts  = (unsigned*)(ws);
    unsigned* starts  = (unsigned*)(ws + 2048);
    float*    scalars = (float*)(ws + 4096);
    float*    T       = (float*)(ws + 4608);
    unsigned* bh      = (unsigned*)(ws + 8192);
    unsigned* idx     = (unsigned*)(ws + 139264);

    k_hist   <<<dim3(HB),   dim3(HT),   0, stream>>>(pids, N, bh, scalars, T);
    k_scatter<<<dim3(HB),   dim3(HT),   0, stream>>>(pids, N, bh, counts,
                                                     starts, idx);
    k_main   <<<dim3(NPAT), dim3(MT),   0, stream>>>(feats, idx, counts, starts,
                                                     T, scalars);
    k_final  <<<dim3(1),    dim3(DIMS), 0, stream>>>(T, scalars, nump, out);
}